// Round 4
// baseline (246.171 us; speedup 1.0000x reference)
//
#include <hip/hip_runtime.h>
#include <hip/hip_bf16.h>

typedef __attribute__((ext_vector_type(4))) float f32x4;
typedef __attribute__((ext_vector_type(8))) short bf16x8;

#define DEV __device__ __forceinline__

DEV unsigned short f2bf(float f) {
  union { float f; unsigned int u; } v; v.f = f;
  unsigned int r = v.u + 0x7fffu + ((v.u >> 16) & 1u);
  return (unsigned short)(r >> 16);
}

DEV float bf2f(unsigned short u) {
  union { unsigned int u; float f; } v; v.u = ((unsigned int)u) << 16; return v.f;
}

DEV short2 pkbf(float a, float b) {
  float2 t; t.x = a; t.y = b;
  __hip_bfloat162 h = __float22bfloat162_rn(t);
  union { __hip_bfloat162 h; short2 s; } u; u.h = h; return u.s;
}

DEV bf16x8 cvt8(float4 u, float4 v) {
  short2 a = pkbf(u.x, u.y), b = pkbf(u.z, u.w), c = pkbf(v.x, v.y), d = pkbf(v.z, v.w);
  bf16x8 r;
  r[0] = a.x; r[1] = a.y; r[2] = b.x; r[3] = b.y;
  r[4] = c.x; r[5] = c.y; r[6] = d.x; r[7] = d.y;
  return r;
}

// tanh-approx gelu via sigmoid form
DEV float gelu_fast(float v) {
  float u = 1.5957691216057308f * v * (1.0f + 0.044715f * v * v);
  return v / (1.0f + __expf(-u));
}

// window token row -> natural (b,t,h,w) flat token index (handles roll both ways)
DEV size_t winmap(int row) {
  int wIdx = row >> 7, n = row & 127;
  int b = wIdx >> 8, widx = wIdx & 255;
  int t = (((widx >> 6) * 2 + (n >> 6)) + 1) & 7;
  int h = ((((widx >> 3) & 7) * 8 + ((n >> 3) & 7)) + 4) & 63;
  int w = (((widx & 7) * 8 + (n & 7)) + 4) & 63;
  return (size_t)(((b * 8 + t) * 64 + h) * 64 + w);
}

// region id for shifted-window mask: tokens in different regions get -100
DEV int reg3(int tw, int hw, int ww, int n) {
  int ts = tw * 2 + (n >> 6);
  int hs = hw * 8 + ((n >> 3) & 7);
  int wsv = ww * 8 + (n & 7);
  int rt = (ts >= 7) ? 2 : ((ts >= 6) ? 1 : 0);
  int rh = (hs >= 60) ? 2 : ((hs >= 56) ? 1 : 0);
  int rw = (wsv >= 60) ? 2 : ((wsv >= 56) ? 1 : 0);
  return rt * 9 + rh * 3 + rw;
}

DEV void gload16(const unsigned short* g, unsigned short* lds) {
  __builtin_amdgcn_global_load_lds(
      (const __attribute__((address_space(1))) unsigned int*)g,
      (__attribute__((address_space(3))) unsigned int*)lds, 16, 0, 0);
}

// ---------------- prep: cast weights to bf16, build per-head rel-pos bias ----------------
__global__ __launch_bounds__(256) void k_prep(
    const float* __restrict__ qkv_w, const float* __restrict__ proj_w,
    const float* __restrict__ fc1_w, const float* __restrict__ fc2_w,
    const float* __restrict__ rpb_t, const int* __restrict__ rpb_i,
    unsigned short* __restrict__ wq, unsigned short* __restrict__ wp,
    unsigned short* __restrict__ w1, unsigned short* __restrict__ w2,
    float* __restrict__ b6) {
  int i = blockIdx.x * 256 + threadIdx.x;
  if (i < 110592) wq[i] = f2bf(qkv_w[i]);
  if (i < 36864)  wp[i] = f2bf(proj_w[i]);
  if (i < 147456) { w1[i] = f2bf(fc1_w[i]); w2[i] = f2bf(fc2_w[i]); }
  if (i < 16384) {
    int idx = rpb_i[i];
    #pragma unroll
    for (int h = 0; h < 6; ++h) b6[h * 16384 + i] = rpb_t[idx * 6 + h];
  }
}

// ---------------- qkv GEMM: gather x (roll+window) fused into A staging ----------------
__global__ __launch_bounds__(256) void k_qkv(
    const float* __restrict__ x, const unsigned short* __restrict__ Bm,
    const float* __restrict__ bias, unsigned short* __restrict__ outb) {
  __shared__ char smem[40960];
  float* As = (float*)smem;                      // [128 rows][16 slots of 16B] swizzled
  unsigned short* Bs = (unsigned short*)(smem + 32768);
  unsigned short* Cs = (unsigned short*)smem;    // epilogue reuse, stride 72
  const int tid = threadIdx.x;
  const int wave = tid >> 6, lane = tid & 63;
  const int lin = ((int)blockIdx.x & 7) * 576 + ((int)blockIdx.x >> 3);
  const int mt = lin / 9, nt = lin - mt * 9;
  const int m0 = mt * 128, n0 = nt * 64;
  const int wr = wave >> 1, wc = wave & 1;
  const int l8 = lane >> 3, s8 = lane & 7;

  const float* aptr[8];
  #pragma unroll
  for (int i = 0; i < 8; ++i) {
    int row = wave * 32 + i * 4 + (lane >> 4);
    aptr[i] = x + winmap(m0 + row) * 192 + (((lane & 15) ^ (row & 15)) << 2);
  }

  f32x4 acc[4][2] = {};
  for (int kt = 0; kt < 192; kt += 64) {
    __syncthreads();
    #pragma unroll
    for (int i = 0; i < 8; ++i)
      gload16((const unsigned short*)(aptr[i] + kt), (unsigned short*)(As + (wave * 8 + i) * 256));
    #pragma unroll
    for (int j = 0; j < 2; ++j) {
      int c = wave * 2 + j;
      int row = c * 8 + l8;
      gload16(Bm + (size_t)(n0 + row) * 192 + kt + (s8 ^ l8) * 8, Bs + c * 512);
    }
    __syncthreads();

    #pragma unroll
    for (int kk = 0; kk < 2; ++kk) {
      bf16x8 af[4], bfr[2];
      #pragma unroll
      for (int mi = 0; mi < 4; ++mi) {
        int r = wr * 64 + mi * 16 + (lane & 15);
        int s0 = kk * 8 + (lane >> 4) * 2;
        float4 u = *(const float4*)(As + r * 64 + ((s0 ^ (r & 15)) << 2));
        float4 v = *(const float4*)(As + r * 64 + (((s0 + 1) ^ (r & 15)) << 2));
        af[mi] = cvt8(u, v);
      }
      #pragma unroll
      for (int ni = 0; ni < 2; ++ni) {
        int row = wc * 32 + ni * 16 + (lane & 15);
        int slot = (kk * 4 + (lane >> 4)) ^ (row & 7);
        bfr[ni] = *(const bf16x8*)(Bs + row * 64 + slot * 8);
      }
      #pragma unroll
      for (int mi = 0; mi < 4; ++mi)
        #pragma unroll
        for (int ni = 0; ni < 2; ++ni)
          acc[mi][ni] = __builtin_amdgcn_mfma_f32_16x16x32_bf16(af[mi], bfr[ni], acc[mi][ni], 0, 0, 0);
    }
  }

  __syncthreads();
  #pragma unroll
  for (int ni = 0; ni < 2; ++ni) {
    int coll = wc * 32 + ni * 16 + (lane & 15);
    float bb = bias[n0 + coll];
    #pragma unroll
    for (int mi = 0; mi < 4; ++mi) {
      int rbase = wr * 64 + mi * 16 + ((lane >> 4) << 2);
      #pragma unroll
      for (int j = 0; j < 4; ++j)
        Cs[(rbase + j) * 72 + coll] = f2bf(acc[mi][ni][j] + bb);
    }
  }
  __syncthreads();
  const int row = tid >> 1, hh = tid & 1;
  unsigned short* gb = outb + (size_t)(m0 + row) * 576 + n0 + hh * 32;
  #pragma unroll
  for (int s = 0; s < 4; ++s)
    *(bf16x8*)(gb + s * 8) = *(const bf16x8*)(Cs + row * 72 + hh * 32 + s * 8);
}

// ---------------- 128x64-tile bf16 GEMM (proj): C = A @ B^T + bias, scatter+residual ----------------
enum { EPI_BF16 = 0, EPI_PROJ = 2 };

template <int EPI, int GATHER>
__global__ __launch_bounds__(256) void gemm_bt(
    const void* __restrict__ Ap, const unsigned short* __restrict__ Bm,
    const float* __restrict__ bias, unsigned short* __restrict__ outb,
    const float* __restrict__ xres, int N, int K, int NT) {
  __shared__ unsigned short sh[128 * 72];
  unsigned short* Bs = sh;
  const int tid = threadIdx.x;
  const int wave = tid >> 6, lane = tid & 63;
  const int total = (int)gridDim.x;
  const int lin = ((int)blockIdx.x & 7) * (total >> 3) + ((int)blockIdx.x >> 3);
  const int mt = lin / NT, nt = lin - mt * NT;
  const int m0 = mt * 128, n0 = nt * 64;
  const int wr = wave >> 1, wc = wave & 1;
  const int l8 = lane >> 3, s8 = lane & 7;
  const unsigned short* Ab = (const unsigned short*)Ap;

  size_t abase[4];
  #pragma unroll
  for (int mi = 0; mi < 4; ++mi) {
    int arow = m0 + wr * 64 + mi * 16 + (lane & 15);
    abase[mi] = (size_t)arow * K;
  }

  f32x4 acc[4][2] = {};
  for (int kt = 0; kt < K; kt += 64) {
    __syncthreads();
    #pragma unroll
    for (int i = 0; i < 2; ++i) {
      int c = wave * 2 + i;
      int row = c * 8 + l8;
      gload16(Bm + (size_t)(n0 + row) * K + kt + (s8 ^ l8) * 8, Bs + c * 512);
    }
    __syncthreads();

    #pragma unroll
    for (int kk = 0; kk < 2; ++kk) {
      bf16x8 af[4], bfr[2];
      #pragma unroll
      for (int mi = 0; mi < 4; ++mi)
        af[mi] = *(const bf16x8*)(Ab + abase[mi] + kt + kk * 32 + (lane >> 4) * 8);
      #pragma unroll
      for (int ni = 0; ni < 2; ++ni) {
        int row = wc * 32 + ni * 16 + (lane & 15);
        int slot = (kk * 4 + (lane >> 4)) ^ (row & 7);
        bfr[ni] = *(const bf16x8*)(Bs + row * 64 + slot * 8);
      }
      #pragma unroll
      for (int mi = 0; mi < 4; ++mi)
        #pragma unroll
        for (int ni = 0; ni < 2; ++ni)
          acc[mi][ni] = __builtin_amdgcn_mfma_f32_16x16x32_bf16(af[mi], bfr[ni], acc[mi][ni], 0, 0, 0);
    }
  }

  __syncthreads();
  #pragma unroll
  for (int ni = 0; ni < 2; ++ni) {
    int coll = wc * 32 + ni * 16 + (lane & 15);
    float bb = bias[n0 + coll];
    #pragma unroll
    for (int mi = 0; mi < 4; ++mi) {
      int rbase = wr * 64 + mi * 16 + ((lane >> 4) << 2);
      #pragma unroll
      for (int j = 0; j < 4; ++j)
        sh[(rbase + j) * 72 + coll] = f2bf(acc[mi][ni][j] + bb);
    }
  }
  __syncthreads();
  const int row = tid >> 1, hh = tid & 1;
  if (EPI == EPI_BF16) {
    unsigned short* gb = outb + (size_t)(m0 + row) * N + n0 + hh * 32;
    #pragma unroll
    for (int s = 0; s < 4; ++s)
      *(bf16x8*)(gb + s * 8) = *(const bf16x8*)(sh + row * 72 + hh * 32 + s * 8);
  } else {
    size_t gf = winmap(m0 + row) * 192 + n0 + hh * 32;
    #pragma unroll
    for (int s = 0; s < 4; ++s) {
      bf16x8 cv = *(const bf16x8*)(sh + row * 72 + hh * 32 + s * 8);
      float4 x0 = *(const float4*)(xres + gf + s * 8);
      float4 x1 = *(const float4*)(xres + gf + s * 8 + 4);
      bf16x8 o;
      o[0] = (short)f2bf(bf2f((unsigned short)cv[0]) + x0.x);
      o[1] = (short)f2bf(bf2f((unsigned short)cv[1]) + x0.y);
      o[2] = (short)f2bf(bf2f((unsigned short)cv[2]) + x0.z);
      o[3] = (short)f2bf(bf2f((unsigned short)cv[3]) + x0.w);
      o[4] = (short)f2bf(bf2f((unsigned short)cv[4]) + x1.x);
      o[5] = (short)f2bf(bf2f((unsigned short)cv[5]) + x1.y);
      o[6] = (short)f2bf(bf2f((unsigned short)cv[6]) + x1.z);
      o[7] = (short)f2bf(bf2f((unsigned short)cv[7]) + x1.w);
      *(bf16x8*)(outb + gf + s * 8) = o;
    }
  }
}

// ---------------- attention: one block per (window, head); mask computed on the fly ----------------
__global__ __launch_bounds__(256) void k_attn(const unsigned short* __restrict__ qkv,
                                              const float* __restrict__ bias6,
                                              unsigned short* __restrict__ attn_out) {
  __shared__ unsigned short Kl[128 * 40];   // [128][32] pad->40
  __shared__ unsigned short Vt[32 * 136];   // V^T [32][128] pad->136
  __shared__ unsigned short Pl[128 * 140];  // P [128][128] pad->140
  const int lin = ((int)blockIdx.x & 7) * 384 + ((int)blockIdx.x >> 3);
  const int wIdx = lin / 6;
  const int hd = lin - wIdx * 6;
  const int tid = threadIdx.x;
  const int wave = tid >> 6, lane = tid & 63;
  const int widx = wIdx & 255;
  const int tw = widx >> 6, hw = (widx >> 3) & 7, ww = widx & 7;
  const size_t qbase = (size_t)wIdx * 73728;

  #pragma unroll
  for (int r = 0; r < 2; ++r) {
    int idx = r * 256 + tid;
    int row = idx >> 2, slot = idx & 3;
    *(bf16x8*)(Kl + row * 40 + slot * 8) =
        *(const bf16x8*)(qkv + qbase + (size_t)row * 576 + 192 + hd * 32 + slot * 8);
  }
  // stage V transposed with all 256 threads (2 slots each)
  {
    int vtok = tid & 127, shalf = tid >> 7;
    #pragma unroll
    for (int so = 0; so < 2; ++so) {
      int slot = shalf * 2 + so;
      bf16x8 v = *(const bf16x8*)(qkv + qbase + (size_t)vtok * 576 + 384 + hd * 32 + slot * 8);
      #pragma unroll
      for (int j = 0; j < 8; ++j)
        Vt[(slot * 8 + j) * 136 + vtok] = (unsigned short)v[j];
    }
  }
  bf16x8 qf[2];
  #pragma unroll
  for (int tr = 0; tr < 2; ++tr)
    qf[tr] = *(const bf16x8*)(qkv + qbase +
                              (size_t)(wave * 32 + tr * 16 + (lane & 15)) * 576 +
                              hd * 32 + (lane >> 4) * 8);
  int rcol[8];
  #pragma unroll
  for (int tc = 0; tc < 8; ++tc) rcol[tc] = reg3(tw, hw, ww, tc * 16 + (lane & 15));
  __syncthreads();

  f32x4 s[2][8];
  #pragma unroll
  for (int tc = 0; tc < 8; ++tc) {
    bf16x8 kf = *(const bf16x8*)(Kl + (tc * 16 + (lane & 15)) * 40 + (lane >> 4) * 8);
    #pragma unroll
    for (int tr = 0; tr < 2; ++tr) {
      f32x4 z = {0.f, 0.f, 0.f, 0.f};
      s[tr][tc] = __builtin_amdgcn_mfma_f32_16x16x32_bf16(qf[tr], kf, z, 0, 0, 0);
    }
  }

  const float scale = 0.17677669529663687f;
  float rsum[2][4];
  #pragma unroll
  for (int tr = 0; tr < 2; ++tr) {
    #pragma unroll
    for (int j = 0; j < 4; ++j) {
      int row = wave * 32 + tr * 16 + ((lane >> 4) << 2) + j;
      const float* bp = bias6 + hd * 16384 + row * 128;
      int rrow = reg3(tw, hw, ww, row);
      float mx = -1e30f;
      #pragma unroll
      for (int tc = 0; tc < 8; ++tc) {
        int col = tc * 16 + (lane & 15);
        float v = s[tr][tc][j] * scale + bp[col] + ((rrow == rcol[tc]) ? 0.0f : -100.0f);
        s[tr][tc][j] = v;
        mx = fmaxf(mx, v);
      }
      #pragma unroll
      for (int d = 1; d < 16; d <<= 1) mx = fmaxf(mx, __shfl_xor(mx, d));
      float sum = 0.f;
      #pragma unroll
      for (int tc = 0; tc < 8; ++tc) {
        float p = __expf(s[tr][tc][j] - mx);
        s[tr][tc][j] = p;
        sum += p;
      }
      #pragma unroll
      for (int d = 1; d < 16; d <<= 1) sum += __shfl_xor(sum, d);
      rsum[tr][j] = sum;
      #pragma unroll
      for (int tc = 0; tc < 8; ++tc)
        Pl[row * 140 + tc * 16 + (lane & 15)] = f2bf(s[tr][tc][j]);
    }
  }
  __syncthreads();

  f32x4 o[2][2] = {};
  #pragma unroll
  for (int ks = 0; ks < 4; ++ks) {
    bf16x8 pa[2], vb[2];
    #pragma unroll
    for (int tr = 0; tr < 2; ++tr)
      pa[tr] = *(const bf16x8*)(Pl + (wave * 32 + tr * 16 + (lane & 15)) * 140 +
                                ks * 32 + (lane >> 4) * 8);
    #pragma unroll
    for (int nc = 0; nc < 2; ++nc)
      vb[nc] = *(const bf16x8*)(Vt + (nc * 16 + (lane & 15)) * 136 +
                                ks * 32 + (lane >> 4) * 8);
    #pragma unroll
    for (int tr = 0; tr < 2; ++tr)
      #pragma unroll
      for (int nc = 0; nc < 2; ++nc)
        o[tr][nc] = __builtin_amdgcn_mfma_f32_16x16x32_bf16(pa[tr], vb[nc], o[tr][nc], 0, 0, 0);
  }

  #pragma unroll
  for (int tr = 0; tr < 2; ++tr)
    #pragma unroll
    for (int nc = 0; nc < 2; ++nc)
      #pragma unroll
      for (int j = 0; j < 4; ++j) {
        int row = wave * 32 + tr * 16 + ((lane >> 4) << 2) + j;
        float v = o[tr][nc][j] * (1.0f / rsum[tr][j]);
        attn_out[((size_t)wIdx * 128 + row) * 192 + hd * 32 + nc * 16 + (lane & 15)] = f2bf(v);
      }
}

// ---------------- fused MLP v2: out = x + gelu(y@w1^T+b1)@w2^T + b2 ----------------
// 128 tokens/block, 512 threads. LDS = Ys 48K + Hs 16K = 64K -> 2 blocks/CU.
// Weights read directly from global (L2-resident). GEMM1 computed TRANSPOSED
// (hT = W1 @ Y^T) so gelu quads run along hidden -> ushort4 LDS writes, float4 bias.
// Hs swizzle: 8B slot s -> s ^ (tok&14)  (even XOR keeps 16B read pairs intact).
__global__ __launch_bounds__(512, 4) void k_mlp(
    const unsigned short* __restrict__ y, const unsigned short* __restrict__ w1,
    const float* __restrict__ b1, const unsigned short* __restrict__ w2,
    const float* __restrict__ b2, const float* __restrict__ xin,
    float* __restrict__ out) {
  __shared__ unsigned short Ys[3 * 8192];    // [p][128 tok][64 cols] XOR-swizzled
  __shared__ unsigned short Hs[128 * 64];    // [tok][64 hid] swizzled
  const int tid = threadIdx.x;
  const int wave = tid >> 6, lane = tid & 63;
  const int l8 = lane >> 3, s8 = lane & 7;
  const int lrow = lane & 15, lk = lane >> 4;
  const int m0 = (int)blockIdx.x * 128;
  const int wh = wave >> 2, wt = wave & 3;     // GEMM1-T: 2 hid-tiles x 4 tok-tiles
  const int w2r = wave >> 2, w2c = wave & 3;   // GEMM2: 2x4 waves over 128x192

  // stage Ys (48 chunks of 1KB)
  #pragma unroll
  for (int i = 0; i < 6; ++i) {
    int c = wave * 6 + i;
    int p = c >> 4, q = c & 15;
    int row = q * 8 + l8;
    gload16(y + (size_t)(m0 + row) * 192 + p * 64 + (s8 ^ l8) * 8, Ys + p * 8192 + q * 512);
  }
  __syncthreads();

  f32x4 oacc[4][3] = {};
  for (int ch = 0; ch < 12; ++ch) {
    const int hb = ch * 64;
    // GEMM1-T: hT[hid][tok] = W1chunk @ Y^T
    f32x4 hacc[2][2] = {};   // [hi][ti]
    #pragma unroll
    for (int kk = 0; kk < 6; ++kk) {
      int p = kk >> 1, half = kk & 1;
      bf16x8 af[2], bfr[2];
      #pragma unroll
      for (int hi = 0; hi < 2; ++hi) {
        int hrow = hb + wh * 32 + hi * 16 + lrow;
        af[hi] = *(const bf16x8*)(w1 + (size_t)hrow * 192 + kk * 32 + lk * 8);
      }
      #pragma unroll
      for (int ti = 0; ti < 2; ++ti) {
        int r = wt * 32 + ti * 16 + lrow;
        int slot = (half * 4 + lk) ^ (r & 7);
        bfr[ti] = *(const bf16x8*)(Ys + p * 8192 + r * 64 + slot * 8);
      }
      #pragma unroll
      for (int hi = 0; hi < 2; ++hi)
        #pragma unroll
        for (int ti = 0; ti < 2; ++ti)
          hacc[hi][ti] = __builtin_amdgcn_mfma_f32_16x16x32_bf16(af[hi], bfr[ti], hacc[hi][ti], 0, 0, 0);
    }
    __syncthreads();   // prev GEMM2 done reading Hs

    // gelu + bias -> Hs, vectorized ushort4 writes (hid quad per thread)
    #pragma unroll
    for (int hi = 0; hi < 2; ++hi) {
      int hid4 = wh * 8 + hi * 4 + lk;          // 8B-slot index 0..15
      float4 bb = *(const float4*)(b1 + hb + hid4 * 4);
      #pragma unroll
      for (int ti = 0; ti < 2; ++ti) {
        int tok = wt * 32 + ti * 16 + lrow;
        short2 p01 = pkbf(gelu_fast(hacc[hi][ti][0] + bb.x), gelu_fast(hacc[hi][ti][1] + bb.y));
        short2 p23 = pkbf(gelu_fast(hacc[hi][ti][2] + bb.z), gelu_fast(hacc[hi][ti][3] + bb.w));
        ushort4 o;
        o.x = (unsigned short)p01.x; o.y = (unsigned short)p01.y;
        o.z = (unsigned short)p23.x; o.w = (unsigned short)p23.y;
        *(ushort4*)(Hs + tok * 64 + ((hid4 ^ (tok & 14)) << 2)) = o;
      }
    }
    __syncthreads();   // Hs visible

    // GEMM2: oacc += H @ W2chunk^T
    #pragma unroll
    for (int kk = 0; kk < 2; ++kk) {
      bf16x8 pa[4], vb[3];
      #pragma unroll
      for (int mi = 0; mi < 4; ++mi) {
        int tok = w2r * 64 + mi * 16 + lrow;
        int s = kk * 8 + lk * 2;
        pa[mi] = *(const bf16x8*)(Hs + tok * 64 + ((s ^ (tok & 14)) << 2));
      }
      #pragma unroll
      for (int ni = 0; ni < 3; ++ni) {
        int n = w2c * 48 + ni * 16 + lrow;
        vb[ni] = *(const bf16x8*)(w2 + (size_t)n * 768 + hb + kk * 32 + lk * 8);
      }
      #pragma unroll
      for (int mi = 0; mi < 4; ++mi)
        #pragma unroll
        for (int ni = 0; ni < 3; ++ni)
          oacc[mi][ni] = __builtin_amdgcn_mfma_f32_16x16x32_bf16(pa[mi], vb[ni], oacc[mi][ni], 0, 0, 0);
    }
  }

  // epilogue: out = x + oacc + b2
  #pragma unroll
  for (int ni = 0; ni < 3; ++ni) {
    int col = w2c * 48 + ni * 16 + lrow;
    float bb = b2[col];
    #pragma unroll
    for (int mi = 0; mi < 4; ++mi) {
      int rbase = m0 + w2r * 64 + mi * 16 + (lk << 2);
      #pragma unroll
      for (int j = 0; j < 4; ++j) {
        size_t idx = (size_t)(rbase + j) * 192 + col;
        out[idx] = xin[idx] + oacc[mi][ni][j] + bb;
      }
    }
  }
}

// ---------------- launch ----------------
extern "C" void kernel_launch(void* const* d_in, const int* in_sizes, int n_in,
                              void* d_out, int out_size, void* d_ws, size_t ws_size,
                              hipStream_t stream) {
  const float* x      = (const float*)d_in[0];
  const float* qkv_w  = (const float*)d_in[2];
  const float* qkv_b  = (const float*)d_in[3];
  const float* proj_w = (const float*)d_in[4];
  const float* proj_b = (const float*)d_in[5];
  const float* rpb_t  = (const float*)d_in[6];
  const int*   rpb_i  = (const int*)d_in[7];
  const float* fc1_w  = (const float*)d_in[8];
  const float* fc1_b  = (const float*)d_in[9];
  const float* fc2_w  = (const float*)d_in[10];
  const float* fc2_b  = (const float*)d_in[11];
  float* out = (float*)d_out;
  char* ws = (char*)d_ws;

  unsigned short* qkv = (unsigned short*)(ws + 0);          // 65536x576 bf16
  unsigned short* att = (unsigned short*)(ws + 75497472);   // 65536x192 bf16
  unsigned short* ybf = (unsigned short*)(ws + 100663296);  // 65536x192 bf16
  unsigned short* wq  = (unsigned short*)(ws + 125829120);
  unsigned short* wp  = (unsigned short*)(ws + 126050304);
  unsigned short* w1  = (unsigned short*)(ws + 126124032);
  unsigned short* w2  = (unsigned short*)(ws + 126418944);
  float*          b6  = (float*)(ws + 126713856);

  k_prep<<<576, 256, 0, stream>>>(qkv_w, proj_w, fc1_w, fc2_w, rpb_t, rpb_i, wq, wp, w1, w2, b6);
  k_qkv<<<4608, 256, 0, stream>>>(x, wq, qkv_b, qkv);
  k_attn<<<3072, 256, 0, stream>>>(qkv, b6, att);
  gemm_bt<EPI_PROJ, 0><<<1536, 256, 0, stream>>>(att, wp, proj_b, ybf, x, 192, 192, 3);
  k_mlp<<<512, 512, 0, stream>>>(ybf, w1, fc1_b, w2, fc2_b, x, out);
}

// Round 5
// 189.819 us; speedup vs baseline: 1.2969x; 1.2969x over previous
//
#include <hip/hip_runtime.h>
#include <hip/hip_bf16.h>

typedef __attribute__((ext_vector_type(4))) float f32x4;
typedef __attribute__((ext_vector_type(8))) short bf16x8;

#define DEV __device__ __forceinline__

DEV unsigned short f2bf(float f) {
  union { float f; unsigned int u; } v; v.f = f;
  unsigned int r = v.u + 0x7fffu + ((v.u >> 16) & 1u);
  return (unsigned short)(r >> 16);
}

DEV float bf2f(unsigned short u) {
  union { unsigned int u; float f; } v; v.u = ((unsigned int)u) << 16; return v.f;
}

DEV short2 pkbf(float a, float b) {
  float2 t; t.x = a; t.y = b;
  __hip_bfloat162 h = __float22bfloat162_rn(t);
  union { __hip_bfloat162 h; short2 s; } u; u.h = h; return u.s;
}

DEV bf16x8 cvt8(float4 u, float4 v) {
  short2 a = pkbf(u.x, u.y), b = pkbf(u.z, u.w), c = pkbf(v.x, v.y), d = pkbf(v.z, v.w);
  bf16x8 r;
  r[0] = a.x; r[1] = a.y; r[2] = b.x; r[3] = b.y;
  r[4] = c.x; r[5] = c.y; r[6] = d.x; r[7] = d.y;
  return r;
}

// tanh-approx gelu via sigmoid form, fast rcp
DEV float gelu_fast(float v) {
  float u = 1.5957691216057308f * v * (1.0f + 0.044715f * v * v);
  return v * __builtin_amdgcn_rcpf(1.0f + __expf(-u));
}

// window token row -> natural (b,t,h,w) flat token index (handles roll both ways)
DEV size_t winmap(int row) {
  int wIdx = row >> 7, n = row & 127;
  int b = wIdx >> 8, widx = wIdx & 255;
  int t = (((widx >> 6) * 2 + (n >> 6)) + 1) & 7;
  int h = ((((widx >> 3) & 7) * 8 + ((n >> 3) & 7)) + 4) & 63;
  int w = (((widx & 7) * 8 + (n & 7)) + 4) & 63;
  return (size_t)(((b * 8 + t) * 64 + h) * 64 + w);
}

// region id for shifted-window mask: tokens in different regions get -100
DEV int reg3(int tw, int hw, int ww, int n) {
  int ts = tw * 2 + (n >> 6);
  int hs = hw * 8 + ((n >> 3) & 7);
  int wsv = ww * 8 + (n & 7);
  int rt = (ts >= 7) ? 2 : ((ts >= 6) ? 1 : 0);
  int rh = (hs >= 60) ? 2 : ((hs >= 56) ? 1 : 0);
  int rw = (wsv >= 60) ? 2 : ((wsv >= 56) ? 1 : 0);
  return rt * 9 + rh * 3 + rw;
}

DEV void gload16(const unsigned short* g, unsigned short* lds) {
  __builtin_amdgcn_global_load_lds(
      (const __attribute__((address_space(1))) unsigned int*)g,
      (__attribute__((address_space(3))) unsigned int*)lds, 16, 0, 0);
}

// ---------------- prep: cast weights to bf16, build per-head rel-pos bias ----------------
__global__ __launch_bounds__(256) void k_prep(
    const float* __restrict__ qkv_w, const float* __restrict__ proj_w,
    const float* __restrict__ fc1_w, const float* __restrict__ fc2_w,
    const float* __restrict__ rpb_t, const int* __restrict__ rpb_i,
    unsigned short* __restrict__ wq, unsigned short* __restrict__ wp,
    unsigned short* __restrict__ w1, unsigned short* __restrict__ w2,
    float* __restrict__ b6) {
  int i = blockIdx.x * 256 + threadIdx.x;
  if (i < 110592) wq[i] = f2bf(qkv_w[i]);
  if (i < 36864)  wp[i] = f2bf(proj_w[i]);
  if (i < 147456) { w1[i] = f2bf(fc1_w[i]); w2[i] = f2bf(fc2_w[i]); }
  if (i < 16384) {
    int idx = rpb_i[i];
    #pragma unroll
    for (int h = 0; h < 6; ++h) b6[h * 16384 + i] = rpb_t[idx * 6 + h];
  }
}

// ---------------- qkv GEMM: gather x (roll+window) fused into A staging ----------------
__global__ __launch_bounds__(256) void k_qkv(
    const float* __restrict__ x, const unsigned short* __restrict__ Bm,
    const float* __restrict__ bias, unsigned short* __restrict__ outb) {
  __shared__ char smem[40960];
  float* As = (float*)smem;                      // [128 rows][16 slots of 16B] swizzled
  unsigned short* Bs = (unsigned short*)(smem + 32768);
  unsigned short* Cs = (unsigned short*)smem;    // epilogue reuse, stride 72
  const int tid = threadIdx.x;
  const int wave = tid >> 6, lane = tid & 63;
  const int lin = ((int)blockIdx.x & 7) * 576 + ((int)blockIdx.x >> 3);
  const int mt = lin / 9, nt = lin - mt * 9;
  const int m0 = mt * 128, n0 = nt * 64;
  const int wr = wave >> 1, wc = wave & 1;
  const int l8 = lane >> 3, s8 = lane & 7;

  const float* aptr[8];
  #pragma unroll
  for (int i = 0; i < 8; ++i) {
    int row = wave * 32 + i * 4 + (lane >> 4);
    aptr[i] = x + winmap(m0 + row) * 192 + (((lane & 15) ^ (row & 15)) << 2);
  }

  f32x4 acc[4][2] = {};
  for (int kt = 0; kt < 192; kt += 64) {
    __syncthreads();
    #pragma unroll
    for (int i = 0; i < 8; ++i)
      gload16((const unsigned short*)(aptr[i] + kt), (unsigned short*)(As + (wave * 8 + i) * 256));
    #pragma unroll
    for (int j = 0; j < 2; ++j) {
      int c = wave * 2 + j;
      int row = c * 8 + l8;
      gload16(Bm + (size_t)(n0 + row) * 192 + kt + (s8 ^ l8) * 8, Bs + c * 512);
    }
    __syncthreads();

    #pragma unroll
    for (int kk = 0; kk < 2; ++kk) {
      bf16x8 af[4], bfr[2];
      #pragma unroll
      for (int mi = 0; mi < 4; ++mi) {
        int r = wr * 64 + mi * 16 + (lane & 15);
        int s0 = kk * 8 + (lane >> 4) * 2;
        float4 u = *(const float4*)(As + r * 64 + ((s0 ^ (r & 15)) << 2));
        float4 v = *(const float4*)(As + r * 64 + (((s0 + 1) ^ (r & 15)) << 2));
        af[mi] = cvt8(u, v);
      }
      #pragma unroll
      for (int ni = 0; ni < 2; ++ni) {
        int row = wc * 32 + ni * 16 + (lane & 15);
        int slot = (kk * 4 + (lane >> 4)) ^ (row & 7);
        bfr[ni] = *(const bf16x8*)(Bs + row * 64 + slot * 8);
      }
      #pragma unroll
      for (int mi = 0; mi < 4; ++mi)
        #pragma unroll
        for (int ni = 0; ni < 2; ++ni)
          acc[mi][ni] = __builtin_amdgcn_mfma_f32_16x16x32_bf16(af[mi], bfr[ni], acc[mi][ni], 0, 0, 0);
    }
  }

  __syncthreads();
  #pragma unroll
  for (int ni = 0; ni < 2; ++ni) {
    int coll = wc * 32 + ni * 16 + (lane & 15);
    float bb = bias[n0 + coll];
    #pragma unroll
    for (int mi = 0; mi < 4; ++mi) {
      int rbase = wr * 64 + mi * 16 + ((lane >> 4) << 2);
      #pragma unroll
      for (int j = 0; j < 4; ++j)
        Cs[(rbase + j) * 72 + coll] = f2bf(acc[mi][ni][j] + bb);
    }
  }
  __syncthreads();
  const int row = tid >> 1, hh = tid & 1;
  unsigned short* gb = outb + (size_t)(m0 + row) * 576 + n0 + hh * 32;
  #pragma unroll
  for (int s = 0; s < 4; ++s)
    *(bf16x8*)(gb + s * 8) = *(const bf16x8*)(Cs + row * 72 + hh * 32 + s * 8);
}

// ---------------- 128x64-tile bf16 GEMM (proj): C = A @ B^T + bias, scatter+residual ----------------
enum { EPI_BF16 = 0, EPI_PROJ = 2 };

template <int EPI, int GATHER>
__global__ __launch_bounds__(256) void gemm_bt(
    const void* __restrict__ Ap, const unsigned short* __restrict__ Bm,
    const float* __restrict__ bias, unsigned short* __restrict__ outb,
    const float* __restrict__ xres, int N, int K, int NT) {
  __shared__ unsigned short sh[128 * 72];
  unsigned short* Bs = sh;
  const int tid = threadIdx.x;
  const int wave = tid >> 6, lane = tid & 63;
  const int total = (int)gridDim.x;
  const int lin = ((int)blockIdx.x & 7) * (total >> 3) + ((int)blockIdx.x >> 3);
  const int mt = lin / NT, nt = lin - mt * NT;
  const int m0 = mt * 128, n0 = nt * 64;
  const int wr = wave >> 1, wc = wave & 1;
  const int l8 = lane >> 3, s8 = lane & 7;
  const unsigned short* Ab = (const unsigned short*)Ap;

  size_t abase[4];
  #pragma unroll
  for (int mi = 0; mi < 4; ++mi) {
    int arow = m0 + wr * 64 + mi * 16 + (lane & 15);
    abase[mi] = (size_t)arow * K;
  }

  f32x4 acc[4][2] = {};
  for (int kt = 0; kt < K; kt += 64) {
    __syncthreads();
    #pragma unroll
    for (int i = 0; i < 2; ++i) {
      int c = wave * 2 + i;
      int row = c * 8 + l8;
      gload16(Bm + (size_t)(n0 + row) * K + kt + (s8 ^ l8) * 8, Bs + c * 512);
    }
    __syncthreads();

    #pragma unroll
    for (int kk = 0; kk < 2; ++kk) {
      bf16x8 af[4], bfr[2];
      #pragma unroll
      for (int mi = 0; mi < 4; ++mi)
        af[mi] = *(const bf16x8*)(Ab + abase[mi] + kt + kk * 32 + (lane >> 4) * 8);
      #pragma unroll
      for (int ni = 0; ni < 2; ++ni) {
        int row = wc * 32 + ni * 16 + (lane & 15);
        int slot = (kk * 4 + (lane >> 4)) ^ (row & 7);
        bfr[ni] = *(const bf16x8*)(Bs + row * 64 + slot * 8);
      }
      #pragma unroll
      for (int mi = 0; mi < 4; ++mi)
        #pragma unroll
        for (int ni = 0; ni < 2; ++ni)
          acc[mi][ni] = __builtin_amdgcn_mfma_f32_16x16x32_bf16(af[mi], bfr[ni], acc[mi][ni], 0, 0, 0);
    }
  }

  __syncthreads();
  #pragma unroll
  for (int ni = 0; ni < 2; ++ni) {
    int coll = wc * 32 + ni * 16 + (lane & 15);
    float bb = bias[n0 + coll];
    #pragma unroll
    for (int mi = 0; mi < 4; ++mi) {
      int rbase = wr * 64 + mi * 16 + ((lane >> 4) << 2);
      #pragma unroll
      for (int j = 0; j < 4; ++j)
        sh[(rbase + j) * 72 + coll] = f2bf(acc[mi][ni][j] + bb);
    }
  }
  __syncthreads();
  const int row = tid >> 1, hh = tid & 1;
  if (EPI == EPI_BF16) {
    unsigned short* gb = outb + (size_t)(m0 + row) * N + n0 + hh * 32;
    #pragma unroll
    for (int s = 0; s < 4; ++s)
      *(bf16x8*)(gb + s * 8) = *(const bf16x8*)(sh + row * 72 + hh * 32 + s * 8);
  } else {
    size_t gf = winmap(m0 + row) * 192 + n0 + hh * 32;
    #pragma unroll
    for (int s = 0; s < 4; ++s) {
      bf16x8 cv = *(const bf16x8*)(sh + row * 72 + hh * 32 + s * 8);
      float4 x0 = *(const float4*)(xres + gf + s * 8);
      float4 x1 = *(const float4*)(xres + gf + s * 8 + 4);
      bf16x8 o;
      o[0] = (short)f2bf(bf2f((unsigned short)cv[0]) + x0.x);
      o[1] = (short)f2bf(bf2f((unsigned short)cv[1]) + x0.y);
      o[2] = (short)f2bf(bf2f((unsigned short)cv[2]) + x0.z);
      o[3] = (short)f2bf(bf2f((unsigned short)cv[3]) + x0.w);
      o[4] = (short)f2bf(bf2f((unsigned short)cv[4]) + x1.x);
      o[5] = (short)f2bf(bf2f((unsigned short)cv[5]) + x1.y);
      o[6] = (short)f2bf(bf2f((unsigned short)cv[6]) + x1.z);
      o[7] = (short)f2bf(bf2f((unsigned short)cv[7]) + x1.w);
      *(bf16x8*)(outb + gf + s * 8) = o;
    }
  }
}

// ---------------- attention: one block per (window, head); mask computed on the fly ----------------
__global__ __launch_bounds__(256) void k_attn(const unsigned short* __restrict__ qkv,
                                              const float* __restrict__ bias6,
                                              unsigned short* __restrict__ attn_out) {
  __shared__ unsigned short Kl[128 * 40];   // [128][32] pad->40
  __shared__ unsigned short Vt[32 * 136];   // V^T [32][128] pad->136
  __shared__ unsigned short Pl[128 * 140];  // P [128][128] pad->140
  const int lin = ((int)blockIdx.x & 7) * 384 + ((int)blockIdx.x >> 3);
  const int wIdx = lin / 6;
  const int hd = lin - wIdx * 6;
  const int tid = threadIdx.x;
  const int wave = tid >> 6, lane = tid & 63;
  const int widx = wIdx & 255;
  const int tw = widx >> 6, hw = (widx >> 3) & 7, ww = widx & 7;
  const size_t qbase = (size_t)wIdx * 73728;

  #pragma unroll
  for (int r = 0; r < 2; ++r) {
    int idx = r * 256 + tid;
    int row = idx >> 2, slot = idx & 3;
    *(bf16x8*)(Kl + row * 40 + slot * 8) =
        *(const bf16x8*)(qkv + qbase + (size_t)row * 576 + 192 + hd * 32 + slot * 8);
  }
  {
    int vtok = tid & 127, shalf = tid >> 7;
    #pragma unroll
    for (int so = 0; so < 2; ++so) {
      int slot = shalf * 2 + so;
      bf16x8 v = *(const bf16x8*)(qkv + qbase + (size_t)vtok * 576 + 384 + hd * 32 + slot * 8);
      #pragma unroll
      for (int j = 0; j < 8; ++j)
        Vt[(slot * 8 + j) * 136 + vtok] = (unsigned short)v[j];
    }
  }
  bf16x8 qf[2];
  #pragma unroll
  for (int tr = 0; tr < 2; ++tr)
    qf[tr] = *(const bf16x8*)(qkv + qbase +
                              (size_t)(wave * 32 + tr * 16 + (lane & 15)) * 576 +
                              hd * 32 + (lane >> 4) * 8);
  int rcol[8];
  #pragma unroll
  for (int tc = 0; tc < 8; ++tc) rcol[tc] = reg3(tw, hw, ww, tc * 16 + (lane & 15));
  __syncthreads();

  f32x4 s[2][8];
  #pragma unroll
  for (int tc = 0; tc < 8; ++tc) {
    bf16x8 kf = *(const bf16x8*)(Kl + (tc * 16 + (lane & 15)) * 40 + (lane >> 4) * 8);
    #pragma unroll
    for (int tr = 0; tr < 2; ++tr) {
      f32x4 z = {0.f, 0.f, 0.f, 0.f};
      s[tr][tc] = __builtin_amdgcn_mfma_f32_16x16x32_bf16(qf[tr], kf, z, 0, 0, 0);
    }
  }

  const float scale = 0.17677669529663687f;
  float rsum[2][4];
  #pragma unroll
  for (int tr = 0; tr < 2; ++tr) {
    #pragma unroll
    for (int j = 0; j < 4; ++j) {
      int row = wave * 32 + tr * 16 + ((lane >> 4) << 2) + j;
      const float* bp = bias6 + hd * 16384 + row * 128;
      int rrow = reg3(tw, hw, ww, row);
      float mx = -1e30f;
      #pragma unroll
      for (int tc = 0; tc < 8; ++tc) {
        int col = tc * 16 + (lane & 15);
        float v = s[tr][tc][j] * scale + bp[col] + ((rrow == rcol[tc]) ? 0.0f : -100.0f);
        s[tr][tc][j] = v;
        mx = fmaxf(mx, v);
      }
      #pragma unroll
      for (int d = 1; d < 16; d <<= 1) mx = fmaxf(mx, __shfl_xor(mx, d));
      float sum = 0.f;
      #pragma unroll
      for (int tc = 0; tc < 8; ++tc) {
        float p = __expf(s[tr][tc][j] - mx);
        s[tr][tc][j] = p;
        sum += p;
      }
      #pragma unroll
      for (int d = 1; d < 16; d <<= 1) sum += __shfl_xor(sum, d);
      rsum[tr][j] = sum;
      #pragma unroll
      for (int tc = 0; tc < 8; ++tc)
        Pl[row * 140 + tc * 16 + (lane & 15)] = f2bf(s[tr][tc][j]);
    }
  }
  __syncthreads();

  f32x4 o[2][2] = {};
  #pragma unroll
  for (int ks = 0; ks < 4; ++ks) {
    bf16x8 pa[2], vb[2];
    #pragma unroll
    for (int tr = 0; tr < 2; ++tr)
      pa[tr] = *(const bf16x8*)(Pl + (wave * 32 + tr * 16 + (lane & 15)) * 140 +
                                ks * 32 + (lane >> 4) * 8);
    #pragma unroll
    for (int nc = 0; nc < 2; ++nc)
      vb[nc] = *(const bf16x8*)(Vt + (nc * 16 + (lane & 15)) * 136 +
                                ks * 32 + (lane >> 4) * 8);
    #pragma unroll
    for (int tr = 0; tr < 2; ++tr)
      #pragma unroll
      for (int nc = 0; nc < 2; ++nc)
        o[tr][nc] = __builtin_amdgcn_mfma_f32_16x16x32_bf16(pa[tr], vb[nc], o[tr][nc], 0, 0, 0);
  }

  #pragma unroll
  for (int tr = 0; tr < 2; ++tr)
    #pragma unroll
    for (int nc = 0; nc < 2; ++nc)
      #pragma unroll
      for (int j = 0; j < 4; ++j) {
        int row = wave * 32 + tr * 16 + ((lane >> 4) << 2) + j;
        float v = o[tr][nc][j] * (1.0f / rsum[tr][j]);
        attn_out[((size_t)wIdx * 128 + row) * 192 + hd * 32 + nc * 16 + (lane & 15)] = f2bf(v);
      }
}

// ---------------- fused MLP v3: out = x + gelu(y@w1^T+b1)@w2^T + b2 ----------------
// 128 tokens/block, 512 threads, hidden chunk 32, 24 chunks.
// LDS = Ys 48K + W1s 12K + W2s 12K + Hs 8K = 80K -> 2 blocks/CU (160K exact).
// GEMM1 computed TRANSPOSED (hT[32 hid][128 tok] = W1chunk @ Y^T) -> ushort4 Hs writes.
// 64B-row buffers (Hs, W2s): 16B-slot swizzle pos = slot ^ ((row>>1)&3) -- octet-verified
// conflict-free for b128 reads, <=2-way for b64 writes. 128B-row buffers: slot ^ (row&7).
__global__ __launch_bounds__(512, 4) void k_mlp(
    const unsigned short* __restrict__ y, const unsigned short* __restrict__ w1,
    const float* __restrict__ b1, const unsigned short* __restrict__ w2,
    const float* __restrict__ b2, const float* __restrict__ xin,
    float* __restrict__ out) {
  __shared__ char smem[81920];
  unsigned short* Ys  = (unsigned short*)smem;            // 3 panels [128][64]
  unsigned short* W1s = (unsigned short*)(smem + 49152);  // 3 panels [32][64]
  unsigned short* W2s = (unsigned short*)(smem + 61440);  // [192][32]
  unsigned short* Hs  = (unsigned short*)(smem + 73728);  // [128][32]
  const int tid = threadIdx.x;
  const int wave = tid >> 6, lane = tid & 63;
  const int l8 = lane >> 3, s8 = lane & 7;
  const int lrow = lane & 15, lk = lane >> 4;
  const int tq = (lrow >> 1) & 3;
  const int m0 = (int)blockIdx.x * 128;
  const int wh = wave >> 2, wt = wave & 3;     // GEMM1-T: 2 hid-tiles x 4 tok-groups
  const int w2r = wave >> 2, w2c = wave & 3;   // GEMM2: 2x4 waves over 128x192

  // prologue: stage Ys (48 chunks) + W(0)
  #pragma unroll
  for (int i = 0; i < 6; ++i) {
    int c = wave * 6 + i;
    int p = c >> 4, q = c & 15;
    gload16(y + (size_t)(m0 + q * 8 + l8) * 192 + p * 64 + (s8 ^ l8) * 8,
            Ys + p * 8192 + q * 512);
  }
  {
    int c1 = wave;
    int p = c1 >> 2, q = c1 & 3;
    gload16(w1 + (size_t)(q * 8 + l8) * 192 + p * 64 + (s8 ^ l8) * 8, W1s + c1 * 512);
    if (wave < 4) {
      int c1b = 8 + wave; int pb = c1b >> 2, qb = c1b & 3;
      gload16(w1 + (size_t)(qb * 8 + l8) * 192 + pb * 64 + (s8 ^ l8) * 8, W1s + c1b * 512);
    }
    int c2 = wave;
    int rg = c2 * 16 + (lane >> 2);
    gload16(w2 + (size_t)rg * 768 + (((lane & 3) ^ ((rg >> 1) & 3)) * 8), W2s + c2 * 512);
    if (wave < 4) {
      int c2b = 8 + wave;
      int rgb = c2b * 16 + (lane >> 2);
      gload16(w2 + (size_t)rgb * 768 + (((lane & 3) ^ ((rgb >> 1) & 3)) * 8), W2s + c2b * 512);
    }
  }

  f32x4 oacc[4][3] = {};
  for (int ch = 0; ch < 24; ++ch) {
    const int hb = ch * 32;
    __syncthreads();   // W(ch) staged (+Ys at ch=0)

    // GEMM1-T: hT[32 hid][128 tok] = W1chunk @ Y^T
    f32x4 hacc[2] = {};
    #pragma unroll
    for (int kk = 0; kk < 6; ++kk) {
      int p = kk >> 1, sub = kk & 1;
      bf16x8 av = *(const bf16x8*)(W1s + p * 2048 + (wh * 16 + lrow) * 64 +
                                   (((sub * 4 + lk) ^ (lrow & 7)) * 8));
      #pragma unroll
      for (int ti = 0; ti < 2; ++ti) {
        int r = wt * 32 + ti * 16 + lrow;
        bf16x8 bv = *(const bf16x8*)(Ys + p * 8192 + r * 64 +
                                     (((sub * 4 + lk) ^ (r & 7)) * 8));
        hacc[ti] = __builtin_amdgcn_mfma_f32_16x16x32_bf16(av, bv, hacc[ti], 0, 0, 0);
      }
    }
    // gelu + bias -> Hs (ushort4 writes, 16B-slot swizzle ^ tq)
    {
      float4 bb = *(const float4*)(b1 + hb + wh * 16 + lk * 4);
      int s16 = wh * 2 + (lk >> 1), half = lk & 1;
      #pragma unroll
      for (int ti = 0; ti < 2; ++ti) {
        int tok = wt * 32 + ti * 16 + lrow;
        short2 p01 = pkbf(gelu_fast(hacc[ti][0] + bb.x), gelu_fast(hacc[ti][1] + bb.y));
        short2 p23 = pkbf(gelu_fast(hacc[ti][2] + bb.z), gelu_fast(hacc[ti][3] + bb.w));
        ushort4 o;
        o.x = (unsigned short)p01.x; o.y = (unsigned short)p01.y;
        o.z = (unsigned short)p23.x; o.w = (unsigned short)p23.y;
        *(ushort4*)(Hs + tok * 32 + ((s16 ^ tq) * 8) + half * 4) = o;
      }
    }
    __syncthreads();   // Hs visible; all waves done with W1s

    // prefetch W1(ch+1) under GEMM2
    if (ch < 23) {
      int c1 = wave;
      int p = c1 >> 2, q = c1 & 3;
      gload16(w1 + (size_t)(hb + 32 + q * 8 + l8) * 192 + p * 64 + (s8 ^ l8) * 8,
              W1s + c1 * 512);
      if (wave < 4) {
        int c1b = 8 + wave; int pb = c1b >> 2, qb = c1b & 3;
        gload16(w1 + (size_t)(hb + 32 + qb * 8 + l8) * 192 + pb * 64 + (s8 ^ l8) * 8,
                W1s + c1b * 512);
      }
    }

    // GEMM2: oacc += H @ W2chunk^T (K=32)
    {
      bf16x8 pa[4], vb[3];
      #pragma unroll
      for (int mi = 0; mi < 4; ++mi) {
        int tok = w2r * 64 + mi * 16 + lrow;
        pa[mi] = *(const bf16x8*)(Hs + tok * 32 + ((lk ^ tq) * 8));
      }
      #pragma unroll
      for (int ni = 0; ni < 3; ++ni) {
        int n = w2c * 48 + ni * 16 + lrow;
        vb[ni] = *(const bf16x8*)(W2s + n * 32 + ((lk ^ tq) * 8));
      }
      #pragma unroll
      for (int mi = 0; mi < 4; ++mi)
        #pragma unroll
        for (int ni = 0; ni < 3; ++ni)
          oacc[mi][ni] = __builtin_amdgcn_mfma_f32_16x16x32_bf16(pa[mi], vb[ni], oacc[mi][ni], 0, 0, 0);
    }
    __syncthreads();   // GEMM2 done; W2s free

    // prefetch W2(ch+1)
    if (ch < 23) {
      int c2 = wave;
      int rg = c2 * 16 + (lane >> 2);
      gload16(w2 + (size_t)rg * 768 + hb + 32 + (((lane & 3) ^ ((rg >> 1) & 3)) * 8),
              W2s + c2 * 512);
      if (wave < 4) {
        int c2b = 8 + wave;
        int rgb = c2b * 16 + (lane >> 2);
        gload16(w2 + (size_t)rgb * 768 + hb + 32 + (((lane & 3) ^ ((rgb >> 1) & 3)) * 8),
                W2s + c2b * 512);
      }
    }
  }

  // epilogue: out = x + oacc + b2
  #pragma unroll
  for (int ni = 0; ni < 3; ++ni) {
    int col = w2c * 48 + ni * 16 + lrow;
    float bb = b2[col];
    #pragma unroll
    for (int mi = 0; mi < 4; ++mi) {
      int rbase = m0 + w2r * 64 + mi * 16 + (lk << 2);
      #pragma unroll
      for (int j = 0; j < 4; ++j) {
        size_t idx = (size_t)(rbase + j) * 192 + col;
        out[idx] = xin[idx] + oacc[mi][ni][j] + bb;
      }
    }
  }
}

// ---------------- launch ----------------
extern "C" void kernel_launch(void* const* d_in, const int* in_sizes, int n_in,
                              void* d_out, int out_size, void* d_ws, size_t ws_size,
                              hipStream_t stream) {
  const float* x      = (const float*)d_in[0];
  const float* qkv_w  = (const float*)d_in[2];
  const float* qkv_b  = (const float*)d_in[3];
  const float* proj_w = (const float*)d_in[4];
  const float* proj_b = (const float*)d_in[5];
  const float* rpb_t  = (const float*)d_in[6];
  const int*   rpb_i  = (const int*)d_in[7];
  const float* fc1_w  = (const float*)d_in[8];
  const float* fc1_b  = (const float*)d_in[9];
  const float* fc2_w  = (const float*)d_in[10];
  const float* fc2_b  = (const float*)d_in[11];
  float* out = (float*)d_out;
  char* ws = (char*)d_ws;

  unsigned short* qkv = (unsigned short*)(ws + 0);          // 65536x576 bf16
  unsigned short* att = (unsigned short*)(ws + 75497472);   // 65536x192 bf16
  unsigned short* ybf = (unsigned short*)(ws + 100663296);  // 65536x192 bf16
  unsigned short* wq  = (unsigned short*)(ws + 125829120);
  unsigned short* wp  = (unsigned short*)(ws + 126050304);
  unsigned short* w1  = (unsigned short*)(ws + 126124032);
  unsigned short* w2  = (unsigned short*)(ws + 126418944);
  float*          b6  = (float*)(ws + 126713856);

  k_prep<<<576, 256, 0, stream>>>(qkv_w, proj_w, fc1_w, fc2_w, rpb_t, rpb_i, wq, wp, w1, w2, b6);
  k_qkv<<<4608, 256, 0, stream>>>(x, wq, qkv_b, qkv);
  k_attn<<<3072, 256, 0, stream>>>(qkv, b6, att);
  gemm_bt<EPI_PROJ, 0><<<1536, 256, 0, stream>>>(att, wp, proj_b, ybf, x, 192, 192, 3);
  k_mlp<<<512, 512, 0, stream>>>(ybf, w1, fc1_b, w2, fc2_b, x, out);
}

// Round 6
// 187.228 us; speedup vs baseline: 1.3148x; 1.0138x over previous
//
#include <hip/hip_runtime.h>
#include <hip/hip_bf16.h>

typedef __attribute__((ext_vector_type(4))) float f32x4;
typedef __attribute__((ext_vector_type(8))) short bf16x8;

#define DEV __device__ __forceinline__

DEV unsigned short f2bf(float f) {
  union { float f; unsigned int u; } v; v.f = f;
  unsigned int r = v.u + 0x7fffu + ((v.u >> 16) & 1u);
  return (unsigned short)(r >> 16);
}

DEV float bf2f(unsigned short u) {
  union { unsigned int u; float f; } v; v.u = ((unsigned int)u) << 16; return v.f;
}

DEV short2 pkbf(float a, float b) {
  float2 t; t.x = a; t.y = b;
  __hip_bfloat162 h = __float22bfloat162_rn(t);
  union { __hip_bfloat162 h; short2 s; } u; u.h = h; return u.s;
}

DEV bf16x8 cvt8(float4 u, float4 v) {
  short2 a = pkbf(u.x, u.y), b = pkbf(u.z, u.w), c = pkbf(v.x, v.y), d = pkbf(v.z, v.w);
  bf16x8 r;
  r[0] = a.x; r[1] = a.y; r[2] = b.x; r[3] = b.y;
  r[4] = c.x; r[5] = c.y; r[6] = d.x; r[7] = d.y;
  return r;
}

// tanh-approx gelu via sigmoid form, fast rcp
DEV float gelu_fast(float v) {
  float u = 1.5957691216057308f * v * (1.0f + 0.044715f * v * v);
  return v * __builtin_amdgcn_rcpf(1.0f + __expf(-u));
}

// window token row -> natural (b,t,h,w) flat token index (handles roll both ways)
DEV size_t winmap(int row) {
  int wIdx = row >> 7, n = row & 127;
  int b = wIdx >> 8, widx = wIdx & 255;
  int t = (((widx >> 6) * 2 + (n >> 6)) + 1) & 7;
  int h = ((((widx >> 3) & 7) * 8 + ((n >> 3) & 7)) + 4) & 63;
  int w = (((widx & 7) * 8 + (n & 7)) + 4) & 63;
  return (size_t)(((b * 8 + t) * 64 + h) * 64 + w);
}

// region id for shifted-window mask: tokens in different regions get -100
DEV int reg3(int tw, int hw, int ww, int n) {
  int ts = tw * 2 + (n >> 6);
  int hs = hw * 8 + ((n >> 3) & 7);
  int wsv = ww * 8 + (n & 7);
  int rt = (ts >= 7) ? 2 : ((ts >= 6) ? 1 : 0);
  int rh = (hs >= 60) ? 2 : ((hs >= 56) ? 1 : 0);
  int rw = (wsv >= 60) ? 2 : ((wsv >= 56) ? 1 : 0);
  return rt * 9 + rh * 3 + rw;
}

DEV void gload16(const unsigned short* g, unsigned short* lds) {
  __builtin_amdgcn_global_load_lds(
      (const __attribute__((address_space(1))) unsigned int*)g,
      (__attribute__((address_space(3))) unsigned int*)lds, 16, 0, 0);
}

// ---------------- prep: cast weights to bf16, build per-head rel-pos bias ----------------
__global__ __launch_bounds__(256) void k_prep(
    const float* __restrict__ qkv_w, const float* __restrict__ proj_w,
    const float* __restrict__ fc1_w, const float* __restrict__ fc2_w,
    const float* __restrict__ rpb_t, const int* __restrict__ rpb_i,
    unsigned short* __restrict__ wq, unsigned short* __restrict__ wp,
    unsigned short* __restrict__ w1, unsigned short* __restrict__ w2,
    float* __restrict__ b6) {
  int i = blockIdx.x * 256 + threadIdx.x;
  if (i < 110592) wq[i] = f2bf(qkv_w[i]);
  if (i < 36864)  wp[i] = f2bf(proj_w[i]);
  if (i < 147456) { w1[i] = f2bf(fc1_w[i]); w2[i] = f2bf(fc2_w[i]); }
  if (i < 16384) {
    int idx = rpb_i[i];
    #pragma unroll
    for (int h = 0; h < 6; ++h) b6[h * 16384 + i] = rpb_t[idx * 6 + h];
  }
}

// ---------------- qkv GEMM: gather x (roll+window) fused into A staging ----------------
__global__ __launch_bounds__(256) void k_qkv(
    const float* __restrict__ x, const unsigned short* __restrict__ Bm,
    const float* __restrict__ bias, unsigned short* __restrict__ outb) {
  __shared__ char smem[40960];
  float* As = (float*)smem;                      // [128 rows][16 slots of 16B] swizzled
  unsigned short* Bs = (unsigned short*)(smem + 32768);
  unsigned short* Cs = (unsigned short*)smem;    // epilogue reuse, stride 72
  const int tid = threadIdx.x;
  const int wave = tid >> 6, lane = tid & 63;
  const int lin = ((int)blockIdx.x & 7) * 576 + ((int)blockIdx.x >> 3);
  const int mt = lin / 9, nt = lin - mt * 9;
  const int m0 = mt * 128, n0 = nt * 64;
  const int wr = wave >> 1, wc = wave & 1;
  const int l8 = lane >> 3, s8 = lane & 7;

  const float* aptr[8];
  #pragma unroll
  for (int i = 0; i < 8; ++i) {
    int row = wave * 32 + i * 4 + (lane >> 4);
    aptr[i] = x + winmap(m0 + row) * 192 + (((lane & 15) ^ (row & 15)) << 2);
  }

  f32x4 acc[4][2] = {};
  for (int kt = 0; kt < 192; kt += 64) {
    __syncthreads();
    #pragma unroll
    for (int i = 0; i < 8; ++i)
      gload16((const unsigned short*)(aptr[i] + kt), (unsigned short*)(As + (wave * 8 + i) * 256));
    #pragma unroll
    for (int j = 0; j < 2; ++j) {
      int c = wave * 2 + j;
      int row = c * 8 + l8;
      gload16(Bm + (size_t)(n0 + row) * 192 + kt + (s8 ^ l8) * 8, Bs + c * 512);
    }
    __syncthreads();

    #pragma unroll
    for (int kk = 0; kk < 2; ++kk) {
      bf16x8 af[4], bfr[2];
      #pragma unroll
      for (int mi = 0; mi < 4; ++mi) {
        int r = wr * 64 + mi * 16 + (lane & 15);
        int s0 = kk * 8 + (lane >> 4) * 2;
        float4 u = *(const float4*)(As + r * 64 + ((s0 ^ (r & 15)) << 2));
        float4 v = *(const float4*)(As + r * 64 + (((s0 + 1) ^ (r & 15)) << 2));
        af[mi] = cvt8(u, v);
      }
      #pragma unroll
      for (int ni = 0; ni < 2; ++ni) {
        int row = wc * 32 + ni * 16 + (lane & 15);
        int slot = (kk * 4 + (lane >> 4)) ^ (row & 7);
        bfr[ni] = *(const bf16x8*)(Bs + row * 64 + slot * 8);
      }
      #pragma unroll
      for (int mi = 0; mi < 4; ++mi)
        #pragma unroll
        for (int ni = 0; ni < 2; ++ni)
          acc[mi][ni] = __builtin_amdgcn_mfma_f32_16x16x32_bf16(af[mi], bfr[ni], acc[mi][ni], 0, 0, 0);
    }
  }

  __syncthreads();
  #pragma unroll
  for (int ni = 0; ni < 2; ++ni) {
    int coll = wc * 32 + ni * 16 + (lane & 15);
    float bb = bias[n0 + coll];
    #pragma unroll
    for (int mi = 0; mi < 4; ++mi) {
      int rbase = wr * 64 + mi * 16 + ((lane >> 4) << 2);
      #pragma unroll
      for (int j = 0; j < 4; ++j)
        Cs[(rbase + j) * 72 + coll] = f2bf(acc[mi][ni][j] + bb);
    }
  }
  __syncthreads();
  const int row = tid >> 1, hh = tid & 1;
  unsigned short* gb = outb + (size_t)(m0 + row) * 576 + n0 + hh * 32;
  #pragma unroll
  for (int s = 0; s < 4; ++s)
    *(bf16x8*)(gb + s * 8) = *(const bf16x8*)(Cs + row * 72 + hh * 32 + s * 8);
}

// ---------------- 128x64-tile bf16 GEMM (proj): C = A @ B^T + bias, scatter+residual ----------------
enum { EPI_BF16 = 0, EPI_PROJ = 2 };

template <int EPI, int GATHER>
__global__ __launch_bounds__(256) void gemm_bt(
    const void* __restrict__ Ap, const unsigned short* __restrict__ Bm,
    const float* __restrict__ bias, unsigned short* __restrict__ outb,
    const float* __restrict__ xres, int N, int K, int NT) {
  __shared__ unsigned short sh[128 * 72];
  unsigned short* Bs = sh;
  const int tid = threadIdx.x;
  const int wave = tid >> 6, lane = tid & 63;
  const int total = (int)gridDim.x;
  const int lin = ((int)blockIdx.x & 7) * (total >> 3) + ((int)blockIdx.x >> 3);
  const int mt = lin / NT, nt = lin - mt * NT;
  const int m0 = mt * 128, n0 = nt * 64;
  const int wr = wave >> 1, wc = wave & 1;
  const int l8 = lane >> 3, s8 = lane & 7;
  const unsigned short* Ab = (const unsigned short*)Ap;

  size_t abase[4];
  #pragma unroll
  for (int mi = 0; mi < 4; ++mi) {
    int arow = m0 + wr * 64 + mi * 16 + (lane & 15);
    abase[mi] = (size_t)arow * K;
  }

  f32x4 acc[4][2] = {};
  for (int kt = 0; kt < K; kt += 64) {
    __syncthreads();
    #pragma unroll
    for (int i = 0; i < 2; ++i) {
      int c = wave * 2 + i;
      int row = c * 8 + l8;
      gload16(Bm + (size_t)(n0 + row) * K + kt + (s8 ^ l8) * 8, Bs + c * 512);
    }
    __syncthreads();

    #pragma unroll
    for (int kk = 0; kk < 2; ++kk) {
      bf16x8 af[4], bfr[2];
      #pragma unroll
      for (int mi = 0; mi < 4; ++mi)
        af[mi] = *(const bf16x8*)(Ab + abase[mi] + kt + kk * 32 + (lane >> 4) * 8);
      #pragma unroll
      for (int ni = 0; ni < 2; ++ni) {
        int row = wc * 32 + ni * 16 + (lane & 15);
        int slot = (kk * 4 + (lane >> 4)) ^ (row & 7);
        bfr[ni] = *(const bf16x8*)(Bs + row * 64 + slot * 8);
      }
      #pragma unroll
      for (int mi = 0; mi < 4; ++mi)
        #pragma unroll
        for (int ni = 0; ni < 2; ++ni)
          acc[mi][ni] = __builtin_amdgcn_mfma_f32_16x16x32_bf16(af[mi], bfr[ni], acc[mi][ni], 0, 0, 0);
    }
  }

  __syncthreads();
  #pragma unroll
  for (int ni = 0; ni < 2; ++ni) {
    int coll = wc * 32 + ni * 16 + (lane & 15);
    float bb = bias[n0 + coll];
    #pragma unroll
    for (int mi = 0; mi < 4; ++mi) {
      int rbase = wr * 64 + mi * 16 + ((lane >> 4) << 2);
      #pragma unroll
      for (int j = 0; j < 4; ++j)
        sh[(rbase + j) * 72 + coll] = f2bf(acc[mi][ni][j] + bb);
    }
  }
  __syncthreads();
  const int row = tid >> 1, hh = tid & 1;
  if (EPI == EPI_BF16) {
    unsigned short* gb = outb + (size_t)(m0 + row) * N + n0 + hh * 32;
    #pragma unroll
    for (int s = 0; s < 4; ++s)
      *(bf16x8*)(gb + s * 8) = *(const bf16x8*)(sh + row * 72 + hh * 32 + s * 8);
  } else {
    size_t gf = winmap(m0 + row) * 192 + n0 + hh * 32;
    #pragma unroll
    for (int s = 0; s < 4; ++s) {
      bf16x8 cv = *(const bf16x8*)(sh + row * 72 + hh * 32 + s * 8);
      float4 x0 = *(const float4*)(xres + gf + s * 8);
      float4 x1 = *(const float4*)(xres + gf + s * 8 + 4);
      bf16x8 o;
      o[0] = (short)f2bf(bf2f((unsigned short)cv[0]) + x0.x);
      o[1] = (short)f2bf(bf2f((unsigned short)cv[1]) + x0.y);
      o[2] = (short)f2bf(bf2f((unsigned short)cv[2]) + x0.z);
      o[3] = (short)f2bf(bf2f((unsigned short)cv[3]) + x0.w);
      o[4] = (short)f2bf(bf2f((unsigned short)cv[4]) + x1.x);
      o[5] = (short)f2bf(bf2f((unsigned short)cv[5]) + x1.y);
      o[6] = (short)f2bf(bf2f((unsigned short)cv[6]) + x1.z);
      o[7] = (short)f2bf(bf2f((unsigned short)cv[7]) + x1.w);
      *(bf16x8*)(outb + gf + s * 8) = o;
    }
  }
}

// ---------------- attention: one block per (window, head); mask computed on the fly ----------------
__global__ __launch_bounds__(256) void k_attn(const unsigned short* __restrict__ qkv,
                                              const float* __restrict__ bias6,
                                              unsigned short* __restrict__ attn_out) {
  __shared__ unsigned short Kl[128 * 40];   // [128][32] pad->40
  __shared__ unsigned short Vt[32 * 136];   // V^T [32][128] pad->136
  __shared__ unsigned short Pl[128 * 140];  // P [128][128] pad->140
  const int lin = ((int)blockIdx.x & 7) * 384 + ((int)blockIdx.x >> 3);
  const int wIdx = lin / 6;
  const int hd = lin - wIdx * 6;
  const int tid = threadIdx.x;
  const int wave = tid >> 6, lane = tid & 63;
  const int widx = wIdx & 255;
  const int tw = widx >> 6, hw = (widx >> 3) & 7, ww = widx & 7;
  const size_t qbase = (size_t)wIdx * 73728;

  #pragma unroll
  for (int r = 0; r < 2; ++r) {
    int idx = r * 256 + tid;
    int row = idx >> 2, slot = idx & 3;
    *(bf16x8*)(Kl + row * 40 + slot * 8) =
        *(const bf16x8*)(qkv + qbase + (size_t)row * 576 + 192 + hd * 32 + slot * 8);
  }
  {
    int vtok = tid & 127, shalf = tid >> 7;
    #pragma unroll
    for (int so = 0; so < 2; ++so) {
      int slot = shalf * 2 + so;
      bf16x8 v = *(const bf16x8*)(qkv + qbase + (size_t)vtok * 576 + 384 + hd * 32 + slot * 8);
      #pragma unroll
      for (int j = 0; j < 8; ++j)
        Vt[(slot * 8 + j) * 136 + vtok] = (unsigned short)v[j];
    }
  }
  bf16x8 qf[2];
  #pragma unroll
  for (int tr = 0; tr < 2; ++tr)
    qf[tr] = *(const bf16x8*)(qkv + qbase +
                              (size_t)(wave * 32 + tr * 16 + (lane & 15)) * 576 +
                              hd * 32 + (lane >> 4) * 8);
  int rcol[8];
  #pragma unroll
  for (int tc = 0; tc < 8; ++tc) rcol[tc] = reg3(tw, hw, ww, tc * 16 + (lane & 15));
  __syncthreads();

  f32x4 s[2][8];
  #pragma unroll
  for (int tc = 0; tc < 8; ++tc) {
    bf16x8 kf = *(const bf16x8*)(Kl + (tc * 16 + (lane & 15)) * 40 + (lane >> 4) * 8);
    #pragma unroll
    for (int tr = 0; tr < 2; ++tr) {
      f32x4 z = {0.f, 0.f, 0.f, 0.f};
      s[tr][tc] = __builtin_amdgcn_mfma_f32_16x16x32_bf16(qf[tr], kf, z, 0, 0, 0);
    }
  }

  const float scale = 0.17677669529663687f;
  float rsum[2][4];
  #pragma unroll
  for (int tr = 0; tr < 2; ++tr) {
    #pragma unroll
    for (int j = 0; j < 4; ++j) {
      int row = wave * 32 + tr * 16 + ((lane >> 4) << 2) + j;
      const float* bp = bias6 + hd * 16384 + row * 128;
      int rrow = reg3(tw, hw, ww, row);
      float mx = -1e30f;
      #pragma unroll
      for (int tc = 0; tc < 8; ++tc) {
        int col = tc * 16 + (lane & 15);
        float v = s[tr][tc][j] * scale + bp[col] + ((rrow == rcol[tc]) ? 0.0f : -100.0f);
        s[tr][tc][j] = v;
        mx = fmaxf(mx, v);
      }
      #pragma unroll
      for (int d = 1; d < 16; d <<= 1) mx = fmaxf(mx, __shfl_xor(mx, d));
      float sum = 0.f;
      #pragma unroll
      for (int tc = 0; tc < 8; ++tc) {
        float p = __expf(s[tr][tc][j] - mx);
        s[tr][tc][j] = p;
        sum += p;
      }
      #pragma unroll
      for (int d = 1; d < 16; d <<= 1) sum += __shfl_xor(sum, d);
      rsum[tr][j] = sum;
      #pragma unroll
      for (int tc = 0; tc < 8; ++tc)
        Pl[row * 140 + tc * 16 + (lane & 15)] = f2bf(s[tr][tc][j]);
    }
  }
  __syncthreads();

  f32x4 o[2][2] = {};
  #pragma unroll
  for (int ks = 0; ks < 4; ++ks) {
    bf16x8 pa[2], vb[2];
    #pragma unroll
    for (int tr = 0; tr < 2; ++tr)
      pa[tr] = *(const bf16x8*)(Pl + (wave * 32 + tr * 16 + (lane & 15)) * 140 +
                                ks * 32 + (lane >> 4) * 8);
    #pragma unroll
    for (int nc = 0; nc < 2; ++nc)
      vb[nc] = *(const bf16x8*)(Vt + (nc * 16 + (lane & 15)) * 136 +
                                ks * 32 + (lane >> 4) * 8);
    #pragma unroll
    for (int tr = 0; tr < 2; ++tr)
      #pragma unroll
      for (int nc = 0; nc < 2; ++nc)
        o[tr][nc] = __builtin_amdgcn_mfma_f32_16x16x32_bf16(pa[tr], vb[nc], o[tr][nc], 0, 0, 0);
  }

  #pragma unroll
  for (int tr = 0; tr < 2; ++tr)
    #pragma unroll
    for (int nc = 0; nc < 2; ++nc)
      #pragma unroll
      for (int j = 0; j < 4; ++j) {
        int row = wave * 32 + tr * 16 + ((lane >> 4) << 2) + j;
        float v = o[tr][nc][j] * (1.0f / rsum[tr][j]);
        attn_out[((size_t)wIdx * 128 + row) * 192 + hd * 32 + nc * 16 + (lane & 15)] = f2bf(v);
      }
}

// ---------------- fused MLP v4: out = x + gelu(y@w1^T+b1)@w2^T + b2 ----------------
// 128 tokens/block, 512 threads (8 waves), wave w owns tokens w*16..w*16+15.
// Y held in REGISTERS (6 bf16x8/lane). Hidden chunk 32, 24 chunks.
// W1/W2 double-buffered in LDS: 2*12K + 2*12K + Hs 8K = 56 KB -> 2 blocks/CU.
// Per chunk: GEMM1-T (hT[32][16] = W1 @ Y^T, 12 MFMA) -> gelu -> Hs (wave-private,
// no barrier) -> GEMM2 (out16 x 192, 12 MFMA) -> ONE barrier -> prefetch W(c+2).
// Prefetch drained a full chunk later => fully covered.
struct WStage { const unsigned short *w1, *w2; };

DEV void stage_w(const unsigned short* w1, const unsigned short* w2, int hb,
                 char* smem, int buf, int wave, int lane) {
  unsigned short* d1 = (unsigned short*)(smem + buf * 12288);
  unsigned short* d2 = (unsigned short*)(smem + 24576 + buf * 12288);
  const int l8 = lane >> 3, s8 = lane & 7;
  // W1 chunk: [3 panels][32 rows][64 cols], 12 gload-chunks (8 rows x 128B each)
  {
    int c = wave, p = c >> 2, q = c & 3;
    gload16(w1 + (size_t)(hb + q * 8 + l8) * 192 + p * 64 + ((s8 ^ l8) * 8), d1 + c * 512);
  }
  if (wave < 4) {
    int c = 8 + wave, p = c >> 2, q = c & 3;
    gload16(w1 + (size_t)(hb + q * 8 + l8) * 192 + p * 64 + ((s8 ^ l8) * 8), d1 + c * 512);
  }
  // W2 chunk: [192 rows][32 cols], 12 gload-chunks (16 rows x 64B each)
  {
    int c = wave;
    int rg = c * 16 + (lane >> 2);
    gload16(w2 + (size_t)rg * 768 + hb + (((lane & 3) ^ ((rg >> 1) & 3)) * 8), d2 + c * 512);
  }
  if (wave < 4) {
    int c = 8 + wave;
    int rg = c * 16 + (lane >> 2);
    gload16(w2 + (size_t)rg * 768 + hb + (((lane & 3) ^ ((rg >> 1) & 3)) * 8), d2 + c * 512);
  }
}

__global__ __launch_bounds__(512, 4) void k_mlp(
    const unsigned short* __restrict__ y, const unsigned short* __restrict__ w1,
    const float* __restrict__ b1, const unsigned short* __restrict__ w2,
    const float* __restrict__ b2, const float* __restrict__ xin,
    float* __restrict__ out) {
  __shared__ char smem[57344];
  unsigned short* Hs = (unsigned short*)(smem + 49152);   // [128][32]
  const int tid = threadIdx.x;
  const int wave = tid >> 6, lane = tid & 63;
  const int lrow = lane & 15, lk = lane >> 4;
  const int m0 = (int)blockIdx.x * 128;
  const int tok = wave * 16 + lrow;          // token row this lane addresses
  const int tq = (lrow >> 1) & 3;            // == ((tok>>1)&3) since wave*16 ≡ 0 mod 8

  // Y fragments in registers: B-frag rows = token (lane&15), k = kk*32 + lk*8
  bf16x8 yfr[6];
  {
    const unsigned short* yp = y + (size_t)(m0 + tok) * 192 + lk * 8;
    #pragma unroll
    for (int kk = 0; kk < 6; ++kk) yfr[kk] = *(const bf16x8*)(yp + kk * 32);
  }

  stage_w(w1, w2, 0, smem, 0, wave, lane);
  stage_w(w1, w2, 32, smem, 1, wave, lane);
  __syncthreads();

  f32x4 oacc[12] = {};
  for (int c = 0; c < 24; ++c) {
    const int hb = c * 32;
    unsigned short* w1b = (unsigned short*)(smem + (c & 1) * 12288);
    unsigned short* w2b = (unsigned short*)(smem + 24576 + (c & 1) * 12288);

    // GEMM1-T: hT[32 hid][16 tok] = W1chunk @ Y^T
    f32x4 hacc[2] = {};
    #pragma unroll
    for (int kk = 0; kk < 6; ++kk) {
      int p = kk >> 1, sc = (kk & 1) * 4;
      #pragma unroll
      for (int hi = 0; hi < 2; ++hi) {
        bf16x8 av = *(const bf16x8*)(w1b + p * 2048 + (hi * 16 + lrow) * 64 +
                                     (((sc + lk) ^ (lrow & 7)) * 8));
        hacc[hi] = __builtin_amdgcn_mfma_f32_16x16x32_bf16(av, yfr[kk], hacc[hi], 0, 0, 0);
      }
    }

    // gelu + bias -> Hs (wave-private region, compiler orders RAW via lgkmcnt)
    #pragma unroll
    for (int hi = 0; hi < 2; ++hi) {
      float4 bb = *(const float4*)(b1 + hb + hi * 16 + lk * 4);
      short2 p01 = pkbf(gelu_fast(hacc[hi][0] + bb.x), gelu_fast(hacc[hi][1] + bb.y));
      short2 p23 = pkbf(gelu_fast(hacc[hi][2] + bb.z), gelu_fast(hacc[hi][3] + bb.w));
      ushort4 o;
      o.x = (unsigned short)p01.x; o.y = (unsigned short)p01.y;
      o.z = (unsigned short)p23.x; o.w = (unsigned short)p23.y;
      int g = hi * 4 + lk;   // 8B granule = hid/4
      *(ushort4*)(Hs + tok * 32 + (((g >> 1) ^ tq) * 8) + (g & 1) * 4) = o;
    }

    // GEMM2: out[16 tok][192] += H[16][32] @ W2chunk^T
    {
      bf16x8 af = *(const bf16x8*)(Hs + tok * 32 + ((lk ^ tq) * 8));
      #pragma unroll
      for (int ni = 0; ni < 12; ++ni) {
        int n = ni * 16 + lrow;
        bf16x8 bv = *(const bf16x8*)(w2b + n * 32 + ((lk ^ ((n >> 1) & 3)) * 8));
        oacc[ni] = __builtin_amdgcn_mfma_f32_16x16x32_bf16(af, bv, oacc[ni], 0, 0, 0);
      }
    }

    __syncthreads();              // all waves done with buf[c&1]; drains W(c+1) loads
    if (c < 22) stage_w(w1, w2, hb + 64, smem, c & 1, wave, lane);
  }

  // epilogue: out = x + oacc + b2
  #pragma unroll
  for (int ni = 0; ni < 12; ++ni) {
    int col = ni * 16 + lrow;
    float bb = b2[col];
    #pragma unroll
    for (int j = 0; j < 4; ++j) {
      size_t idx = (size_t)(m0 + wave * 16 + lk * 4 + j) * 192 + col;
      out[idx] = xin[idx] + oacc[ni][j] + bb;
    }
  }
}

// ---------------- launch ----------------
extern "C" void kernel_launch(void* const* d_in, const int* in_sizes, int n_in,
                              void* d_out, int out_size, void* d_ws, size_t ws_size,
                              hipStream_t stream) {
  const float* x      = (const float*)d_in[0];
  const float* qkv_w  = (const float*)d_in[2];
  const float* qkv_b  = (const float*)d_in[3];
  const float* proj_w = (const float*)d_in[4];
  const float* proj_b = (const float*)d_in[5];
  const float* rpb_t  = (const float*)d_in[6];
  const int*   rpb_i  = (const int*)d_in[7];
  const float* fc1_w  = (const float*)d_in[8];
  const float* fc1_b  = (const float*)d_in[9];
  const float* fc2_w  = (const float*)d_in[10];
  const float* fc2_b  = (const float*)d_in[11];
  float* out = (float*)d_out;
  char* ws = (char*)d_ws;

  unsigned short* qkv = (unsigned short*)(ws + 0);          // 65536x576 bf16
  unsigned short* att = (unsigned short*)(ws + 75497472);   // 65536x192 bf16
  unsigned short* ybf = (unsigned short*)(ws + 100663296);  // 65536x192 bf16
  unsigned short* wq  = (unsigned short*)(ws + 125829120);
  unsigned short* wp  = (unsigned short*)(ws + 126050304);
  unsigned short* w1  = (unsigned short*)(ws + 126124032);
  unsigned short* w2  = (unsigned short*)(ws + 126418944);
  float*          b6  = (float*)(ws + 126713856);

  k_prep<<<576, 256, 0, stream>>>(qkv_w, proj_w, fc1_w, fc2_w, rpb_t, rpb_i, wq, wp, w1, w2, b6);
  k_qkv<<<4608, 256, 0, stream>>>(x, wq, qkv_b, qkv);
  k_attn<<<3072, 256, 0, stream>>>(qkv, b6, att);
  gemm_bt<EPI_PROJ, 0><<<1536, 256, 0, stream>>>(att, wp, proj_b, ybf, x, 192, 192, 3);
  k_mlp<<<512, 512, 0, stream>>>(ybf, w1, fc1_b, w2, fc2_b, x, out);
}